// Round 13
// baseline (29.015 us; speedup 1.0000x reference)
//
#include <hip/hip_runtime.h>
#include <hip/hip_bf16.h>
#include <math.h>

#define Bn 2
#define Kn 8
#define Cn 256
#define HWn (128*128)
#define Sn 2048
#define BT 64             // sim block output tile (4 waves, 2x2 of 32x32)
#define BKc 256           // k-slice: full C staged in ONE LDS fill
#define NT (Sn / BT)      // 32 tile-rows
#define NTRI (NT*(NT+1)/2)   // 528 upper-triangle blocks per batch
#define NPART (NTRI * Bn)    // 1056
#define TLH 128           // gatherT h-tile width

typedef __bf16 bf16x8 __attribute__((ext_vector_type(8)));
typedef float  f32x4  __attribute__((ext_vector_type(4)));

__device__ __forceinline__ void gload_lds16(const ushort* g, ushort* l) {
    __builtin_amdgcn_global_load_lds(
        (const __attribute__((address_space(1))) void*)g,
        (__attribute__((address_space(3))) void*)l,
        16, 0, 0);
}

__device__ __forceinline__ float bf16_to_f32(ushort u) {
    union { unsigned int i; float f; } cv;
    cv.i = ((unsigned int)u) << 16;
    return cv.f;
}
__device__ __forceinline__ ushort f32_to_bf16u(float f) {
    __hip_bfloat16 hv = __float2bfloat16(f);
    return *reinterpret_cast<const ushort*>(&hv);
}

// ---- fused gather (r11 config, proven best): stream feats coalesced,
// keep only sampled columns. One block per (b, 128-wide h-tile), 512 thr,
// LDS [256 c][128 h] bf16; membership scan; wave-per-sampled-column.
__global__ __launch_bounds__(512) void gatherT_kernel(
    const float* __restrict__ masks, const float* __restrict__ feats,
    const int* __restrict__ indices, ushort* __restrict__ fTb,
    float* __restrict__ mS)
{
    __shared__ ushort tile[Cn][TLH + 4];   // stride 132 ushorts (264 B)
    __shared__ int smap[TLH];

    const int b  = blockIdx.y;
    const int h0 = blockIdx.x * TLH;
    const int t  = threadIdx.x;
    const int lane = t & 63;
    const int wave = t >> 6;

    if (t < TLH) smap[t] = -1;
    __syncthreads();

    // membership scan: 2048 indices, 4 per thread (permutation -> no races)
    #pragma unroll
    for (int i = 0; i < 4; ++i) {
        const int s  = t * 4 + i;
        const int d  = indices[b * Sn + s] - h0;
        if ((unsigned)d < TLH) smap[d] = s;
    }

    // coalesced tile load: c = (t>>5)+16*it, h4 = (t&31)*4
    const float* fb = feats + ((size_t)b * Cn) * HWn + h0;
    const int c_l = t >> 5;        // 0..15
    const int h4  = (t & 31) * 4;  // 0..124
    #pragma unroll
    for (int it = 0; it < 16; ++it) {
        const int c = c_l + 16 * it;
        const float4 v = *reinterpret_cast<const float4*>(fb + (size_t)c * HWn + h4);
        ushort4 u;
        u.x = f32_to_bf16u(v.x); u.y = f32_to_bf16u(v.y);
        u.z = f32_to_bf16u(v.z); u.w = f32_to_bf16u(v.w);
        *reinterpret_cast<ushort4*>(&tile[c][h4]) = u;
    }
    __syncthreads();

    // wave per sampled column (8 waves stride the 128 slots)
    for (int hs = wave; hs < TLH; hs += 8) {
        const int p = smap[hs];
        if (p < 0) continue;
        float v[4];
        #pragma unroll
        for (int q = 0; q < 4; ++q)
            v[q] = bf16_to_f32(tile[lane + 64 * q][hs]);
        float x = v[0]*v[0] + v[1]*v[1] + v[2]*v[2] + v[3]*v[3];
        #pragma unroll
        for (int o = 32; o > 0; o >>= 1) x += __shfl_xor(x, o);
        const float scale = 1.0f / fmaxf(sqrtf(x), 1e-12f);
        #pragma unroll
        for (int q = 0; q < 4; ++q)
            fTb[(size_t)(b * Sn + p) * Cn + lane + 64 * q] =
                f32_to_bf16u(v[q] * scale);
        if (lane < Kn) {
            const float lg = masks[((size_t)(b * Kn + lane)) * HWn + h0 + hs];
            mS[(size_t)(b * Sn + p) * Kn + lane] = 1.0f / (1.0f + expf(-lg));
        }
    }
}

// MFMA Gram matrix over upper-triangle 64x64 tile pairs; SINGLE-stage
// BKc=256 staging (16 gload_lds in flight/thread, ONE barrier/block),
// involution swizzle (32 chunks/row). 4 waves (2x2) of 32x32; 64 KB LDS
// -> 2 blocks/CU. Plain-store partials.
__global__ __launch_bounds__(256, 2) void sim_kernel(
    const ushort* __restrict__ fTb, const float* __restrict__ mS,
    float* __restrict__ part)
{
    __shared__ ushort ldsA[BT * BKc];   // 32 KB
    __shared__ ushort ldsB[BT * BKc];   // 32 KB

    const int b = blockIdx.y;
    // decode upper-triangle pair (i <= j) from blockIdx.x
    int i = 0, rem = blockIdx.x;
    while (rem >= NT - i) { rem -= NT - i; ++i; }
    const int j  = i + rem;
    const int s0 = i * BT;
    const int t0 = j * BT;

    const int tid = threadIdx.x;
    const int lane = tid & 63;
    const int wave = tid >> 6;          // 0..3
    const int wm = wave >> 1;           // 0..1 : 32-row slab
    const int wn = wave & 1;            // 0..1 : 32-col slab
    const int l15 = lane & 15, l4 = lane >> 4;

    const ushort* FA = fTb + ((size_t)(b * Sn + s0)) * Cn;
    const ushort* FB = fTb + ((size_t)(b * Sn + t0)) * Cn;

    f32x4 acc[2][2];
    #pragma unroll
    for (int m = 0; m < 2; ++m)
        #pragma unroll
        for (int n = 0; n < 2; ++n) acc[m][n] = (f32x4){0.f, 0.f, 0.f, 0.f};

    // stage: 2048 16B-chunks per matrix (64 rows x 32 chunks); 256 thr x 8.
    // LDS slot (row,c) <- global chunk (c ^ (row&15))  [involution]
    #pragma unroll
    for (int i2 = 0; i2 < 8; ++i2) {
        const int q   = tid + i2 * 256;         // 0..2047
        const int row = q >> 5;                 // 0..63
        const int csw = (q & 31) ^ (row & 15);
        const size_t goff = (size_t)row * Cn + csw * 8;
        gload_lds16(FA + goff, &ldsA[q * 8]);
        gload_lds16(FB + goff, &ldsB[q * 8]);
    }
    __syncthreads();   // single vmcnt drain per block

    #pragma unroll
    for (int kk = 0; kk < BKc; kk += 32) {
        const int g = (kk >> 3) + l4;           // chunk 0..31
        bf16x8 aF[2], bF[2];
        #pragma unroll
        for (int m = 0; m < 2; ++m) {
            const int row = wm * 32 + m * 16 + l15;
            aF[m] = *reinterpret_cast<const bf16x8*>(
                &ldsA[row * BKc + ((g ^ (row & 15)) << 3)]);
        }
        #pragma unroll
        for (int n = 0; n < 2; ++n) {
            const int row = wn * 32 + n * 16 + l15;
            bF[n] = *reinterpret_cast<const bf16x8*>(
                &ldsB[row * BKc + ((g ^ (row & 15)) << 3)]);
        }
        #pragma unroll
        for (int m = 0; m < 2; ++m)
            #pragma unroll
            for (int n = 0; n < 2; ++n)
                acc[m][n] = __builtin_amdgcn_mfma_f32_16x16x32_bf16(
                    aF[m], bF[n], acc[m][n], 0, 0, 0);
    }

    // C/D layout: col = lane&15, row = (lane>>4)*4 + reg  [HW-verified m89]
    // Count only strict-upper pairs (srow < tcol); doubled in finalize.
    float num_l = 0.0f, den_l = 0.0f;
    const float* mSb = mS + (size_t)b * Sn * Kn;
    #pragma unroll
    for (int m = 0; m < 2; ++m) {
        #pragma unroll
        for (int n = 0; n < 2; ++n) {
            #pragma unroll
            for (int r = 0; r < 4; ++r) {
                const int srow = s0 + wm * 32 + m * 16 + l4 * 4 + r;
                const int tcol = t0 + wn * 32 + n * 16 + l15;
                if (acc[m][n][r] > 0.95f && srow < tcol) {
                    den_l += 1.0f;
                    const float* ma = mSb + (size_t)srow * Kn;
                    const float* mb = mSb + (size_t)tcol * Kn;
                    #pragma unroll
                    for (int k = 0; k < Kn; ++k) num_l += fabsf(ma[k] - mb[k]);
                }
            }
        }
    }

    #pragma unroll
    for (int o = 32; o > 0; o >>= 1) {
        num_l += __shfl_down(num_l, o);
        den_l += __shfl_down(den_l, o);
    }
    __shared__ float rn[4], rd[4];
    if (lane == 0) { rn[wave] = num_l; rd[wave] = den_l; }
    __syncthreads();
    if (tid == 0) {
        const int bid = blockIdx.y * NTRI + blockIdx.x;
        part[2 * bid]     = rn[0] + rn[1] + rn[2] + rn[3];
        part[2 * bid + 1] = rd[0] + rd[1] + rd[2] + rd[3];
    }
}

// Reduce NPART {num,den} pairs; out = 2n / (2d + B*S + eps).
__global__ __launch_bounds__(256) void finalize_kernel(
    const float* __restrict__ part, float* __restrict__ out)
{
    const int tid = threadIdx.x;
    float n = 0.f, d = 0.f;
    #pragma unroll
    for (int i = 0; i < 5; ++i) {
        const int idx = tid + 256 * i;
        if (idx < NPART) {
            const float2 p = reinterpret_cast<const float2*>(part)[idx];
            n += p.x; d += p.y;
        }
    }
    #pragma unroll
    for (int o = 32; o > 0; o >>= 1) {
        n += __shfl_down(n, o);
        d += __shfl_down(d, o);
    }
    __shared__ float sn[4], sd[4];
    if ((tid & 63) == 0) { sn[tid >> 6] = n; sd[tid >> 6] = d; }
    __syncthreads();
    if (tid == 0) {
        const float fn = 2.0f * (sn[0] + sn[1] + sn[2] + sn[3]);
        const float fd = 2.0f * (sd[0] + sd[1] + sd[2] + sd[3])
                       + (float)(Bn * Sn);
        out[0] = fn / (fd + 1e-6f);
    }
}

extern "C" void kernel_launch(void* const* d_in, const int* in_sizes, int n_in,
                              void* d_out, int out_size, void* d_ws, size_t ws_size,
                              hipStream_t stream) {
    const float* masks   = (const float*)d_in[0];   // (B,K,H,W) fp32
    const float* feats   = (const float*)d_in[1];   // (B,C,H,W) fp32
    const int*   indices = (const int*)d_in[2];     // (B,S) int32
    float* out = (float*)d_out;

    // ws: fTb (2MB) | mS (128KB) | part (NPART*2 f32)
    const size_t fTb_b = (size_t)Bn * Sn * Cn * sizeof(ushort);
    const size_t mS_b  = (size_t)Bn * Sn * Kn * sizeof(float);

    ushort* fTb  = (ushort*)d_ws;
    float*  mSm  = (float*)((char*)d_ws + fTb_b);
    float*  part = (float*)((char*)d_ws + fTb_b + mS_b);

    dim3 gg(HWn / TLH, Bn);     // (128, 2)
    gatherT_kernel<<<gg, 512, 0, stream>>>(masks, feats, indices, fTb, mSm);
    dim3 grid(NTRI, Bn);        // (528, 2)
    sim_kernel<<<grid, 256, 0, stream>>>(fTb, mSm, part);
    finalize_kernel<<<1, 256, 0, stream>>>(part, out);
}

// Round 14
// 26.640 us; speedup vs baseline: 1.0891x; 1.0891x over previous
//
#include <hip/hip_runtime.h>
#include <hip/hip_bf16.h>
#include <math.h>

#define Bn 2
#define Kn 8
#define Cn 256
#define HWn (128*128)
#define Sn 2048
#define BT 64             // sim block output tile (4 waves, 2x2 of 32x32)
#define BKc 128           // k-slice width (ushorts) staged per LDS fill
#define NSTAGE (Cn / BKc) // 2
#define NT (Sn / BT)      // 32 tile-rows
#define NTRI (NT*(NT+1)/2)   // 528 upper-triangle blocks per batch
#define NPART (NTRI * Bn)    // 1056
#define TLH 128           // gatherT h-tile width

typedef __bf16 bf16x8 __attribute__((ext_vector_type(8)));
typedef float  f32x4  __attribute__((ext_vector_type(4)));

__device__ __forceinline__ void gload_lds16(const ushort* g, ushort* l) {
    __builtin_amdgcn_global_load_lds(
        (const __attribute__((address_space(1))) void*)g,
        (__attribute__((address_space(3))) void*)l,
        16, 0, 0);
}

__device__ __forceinline__ float bf16_to_f32(ushort u) {
    union { unsigned int i; float f; } cv;
    cv.i = ((unsigned int)u) << 16;
    return cv.f;
}
__device__ __forceinline__ ushort f32_to_bf16u(float f) {
    __hip_bfloat16 hv = __float2bfloat16(f);
    return *reinterpret_cast<const ushort*>(&hv);
}

// ---- fused gather: stream feats coalesced, keep only sampled columns ----
// One block per (b, 128-wide h-tile): 512 thr, LDS [256 c][128 h] bf16,
// membership scan, wave-per-sampled-column normalize + write + sigmoid.
__global__ __launch_bounds__(512) void gatherT_kernel(
    const float* __restrict__ masks, const float* __restrict__ feats,
    const int* __restrict__ indices, ushort* __restrict__ fTb,
    float* __restrict__ mS)
{
    __shared__ ushort tile[Cn][TLH + 4];   // stride 132 ushorts (264 B)
    __shared__ int smap[TLH];

    const int b  = blockIdx.y;
    const int h0 = blockIdx.x * TLH;
    const int t  = threadIdx.x;
    const int lane = t & 63;
    const int wave = t >> 6;

    if (t < TLH) smap[t] = -1;
    __syncthreads();

    // membership scan: 2048 indices, 4 per thread (permutation -> no races)
    #pragma unroll
    for (int i = 0; i < 4; ++i) {
        const int s  = t * 4 + i;
        const int d  = indices[b * Sn + s] - h0;
        if ((unsigned)d < TLH) smap[d] = s;
    }

    // coalesced tile load: c = (t>>5)+16*it, h4 = (t&31)*4
    const float* fb = feats + ((size_t)b * Cn) * HWn + h0;
    const int c_l = t >> 5;        // 0..15
    const int h4  = (t & 31) * 4;  // 0..124
    #pragma unroll
    for (int it = 0; it < 16; ++it) {
        const int c = c_l + 16 * it;
        const float4 v = *reinterpret_cast<const float4*>(fb + (size_t)c * HWn + h4);
        ushort4 u;
        u.x = f32_to_bf16u(v.x); u.y = f32_to_bf16u(v.y);
        u.z = f32_to_bf16u(v.z); u.w = f32_to_bf16u(v.w);
        *reinterpret_cast<ushort4*>(&tile[c][h4]) = u;
    }
    __syncthreads();

    // wave per sampled column (8 waves stride the 128 slots)
    for (int hs = wave; hs < TLH; hs += 8) {
        const int p = smap[hs];
        if (p < 0) continue;
        float v[4];
        #pragma unroll
        for (int q = 0; q < 4; ++q)
            v[q] = bf16_to_f32(tile[lane + 64 * q][hs]);
        float x = v[0]*v[0] + v[1]*v[1] + v[2]*v[2] + v[3]*v[3];
        #pragma unroll
        for (int o = 32; o > 0; o >>= 1) x += __shfl_xor(x, o);
        const float scale = 1.0f / fmaxf(sqrtf(x), 1e-12f);
        #pragma unroll
        for (int q = 0; q < 4; ++q)
            fTb[(size_t)(b * Sn + p) * Cn + lane + 64 * q] =
                f32_to_bf16u(v[q] * scale);
        if (lane < Kn) {
            const float lg = masks[((size_t)(b * Kn + lane)) * HWn + h0 + hs];
            mS[(size_t)(b * Sn + p) * Kn + lane] = 1.0f / (1.0f + expf(-lg));
        }
    }
}

// MFMA Gram matrix over upper-triangle 64x64 tile pairs (1056 blocks =
// 4.1 rounds of 256 CUs -> balanced). 4 waves (2x2) of 32x32; BK=128
// single-buffered staging, involution swizzle. Plain-store partials.
__global__ __launch_bounds__(256, 4) void sim_kernel(
    const ushort* __restrict__ fTb, const float* __restrict__ mS,
    float* __restrict__ part)
{
    __shared__ ushort ldsA[BT * BKc];   // 16 KB
    __shared__ ushort ldsB[BT * BKc];   // 16 KB

    const int b = blockIdx.y;
    // decode upper-triangle pair (i <= j) from blockIdx.x
    int i = 0, rem = blockIdx.x;
    while (rem >= NT - i) { rem -= NT - i; ++i; }
    const int j  = i + rem;
    const int s0 = i * BT;
    const int t0 = j * BT;

    const int tid = threadIdx.x;
    const int lane = tid & 63;
    const int wave = tid >> 6;          // 0..3
    const int wm = wave >> 1;           // 0..1 : 32-row slab
    const int wn = wave & 1;            // 0..1 : 32-col slab
    const int l15 = lane & 15, l4 = lane >> 4;

    const ushort* FA = fTb + ((size_t)(b * Sn + s0)) * Cn;
    const ushort* FB = fTb + ((size_t)(b * Sn + t0)) * Cn;

    f32x4 acc[2][2];
    #pragma unroll
    for (int m = 0; m < 2; ++m)
        #pragma unroll
        for (int n = 0; n < 2; ++n) acc[m][n] = (f32x4){0.f, 0.f, 0.f, 0.f};

    #pragma unroll
    for (int st = 0; st < NSTAGE; ++st) {
        const int k0 = st * BKc;
        // stage: 1024 16B-chunks/matrix; 256 thr x 4; involution swizzle
        #pragma unroll
        for (int i2 = 0; i2 < 4; ++i2) {
            const int q   = tid + i2 * 256;         // 0..1023
            const int row = q >> 4;                 // 0..63
            const int csw = (q & 15) ^ (row & 15);
            const size_t goff = (size_t)row * Cn + k0 + csw * 8;
            gload_lds16(FA + goff, &ldsA[q * 8]);
            gload_lds16(FB + goff, &ldsB[q * 8]);
        }
        __syncthreads();

        #pragma unroll
        for (int kk = 0; kk < BKc; kk += 32) {
            const int g = (kk >> 3) + l4;           // chunk 0..15
            bf16x8 aF[2], bF[2];
            #pragma unroll
            for (int m = 0; m < 2; ++m) {
                const int row = wm * 32 + m * 16 + l15;
                aF[m] = *reinterpret_cast<const bf16x8*>(
                    &ldsA[row * BKc + ((g ^ (row & 15)) << 3)]);
            }
            #pragma unroll
            for (int n = 0; n < 2; ++n) {
                const int row = wn * 32 + n * 16 + l15;
                bF[n] = *reinterpret_cast<const bf16x8*>(
                    &ldsB[row * BKc + ((g ^ (row & 15)) << 3)]);
            }
            #pragma unroll
            for (int m = 0; m < 2; ++m)
                #pragma unroll
                for (int n = 0; n < 2; ++n)
                    acc[m][n] = __builtin_amdgcn_mfma_f32_16x16x32_bf16(
                        aF[m], bF[n], acc[m][n], 0, 0, 0);
        }
        __syncthreads();
    }

    // C/D layout: col = lane&15, row = (lane>>4)*4 + reg  [HW-verified m89]
    // Count only strict-upper pairs (srow < tcol); doubled in finalize.
    float num_l = 0.0f, den_l = 0.0f;
    const float* mSb = mS + (size_t)b * Sn * Kn;
    #pragma unroll
    for (int m = 0; m < 2; ++m) {
        #pragma unroll
        for (int n = 0; n < 2; ++n) {
            #pragma unroll
            for (int r = 0; r < 4; ++r) {
                const int srow = s0 + wm * 32 + m * 16 + l4 * 4 + r;
                const int tcol = t0 + wn * 32 + n * 16 + l15;
                if (acc[m][n][r] > 0.95f && srow < tcol) {
                    den_l += 1.0f;
                    const float* ma = mSb + (size_t)srow * Kn;
                    const float* mb = mSb + (size_t)tcol * Kn;
                    #pragma unroll
                    for (int k = 0; k < Kn; ++k) num_l += fabsf(ma[k] - mb[k]);
                }
            }
        }
    }

    #pragma unroll
    for (int o = 32; o > 0; o >>= 1) {
        num_l += __shfl_down(num_l, o);
        den_l += __shfl_down(den_l, o);
    }
    __shared__ float rn[4], rd[4];
    if (lane == 0) { rn[wave] = num_l; rd[wave] = den_l; }
    __syncthreads();
    if (tid == 0) {
        const int bid = blockIdx.y * NTRI + blockIdx.x;
        part[2 * bid]     = rn[0] + rn[1] + rn[2] + rn[3];
        part[2 * bid + 1] = rd[0] + rd[1] + rd[2] + rd[3];
    }
}

// Reduce NPART {num,den} pairs; out = 2n / (2d + B*S + eps).
__global__ __launch_bounds__(256) void finalize_kernel(
    const float* __restrict__ part, float* __restrict__ out)
{
    const int tid = threadIdx.x;
    float n = 0.f, d = 0.f;
    #pragma unroll
    for (int i = 0; i < 5; ++i) {
        const int idx = tid + 256 * i;
        if (idx < NPART) {
            const float2 p = reinterpret_cast<const float2*>(part)[idx];
            n += p.x; d += p.y;
        }
    }
    #pragma unroll
    for (int o = 32; o > 0; o >>= 1) {
        n += __shfl_down(n, o);
        d += __shfl_down(d, o);
    }
    __shared__ float sn[4], sd[4];
    if ((tid & 63) == 0) { sn[tid >> 6] = n; sd[tid >> 6] = d; }
    __syncthreads();
    if (tid == 0) {
        const float fn = 2.0f * (sn[0] + sn[1] + sn[2] + sn[3]);
        const float fd = 2.0f * (sd[0] + sd[1] + sd[2] + sd[3])
                       + (float)(Bn * Sn);
        out[0] = fn / (fd + 1e-6f);
    }
}

extern "C" void kernel_launch(void* const* d_in, const int* in_sizes, int n_in,
                              void* d_out, int out_size, void* d_ws, size_t ws_size,
                              hipStream_t stream) {
    const float* masks   = (const float*)d_in[0];   // (B,K,H,W) fp32
    const float* feats   = (const float*)d_in[1];   // (B,C,H,W) fp32
    const int*   indices = (const int*)d_in[2];     // (B,S) int32
    float* out = (float*)d_out;

    // ws: fTb (2MB) | mS (128KB) | part (NPART*2 f32)
    const size_t fTb_b = (size_t)Bn * Sn * Cn * sizeof(ushort);
    const size_t mS_b  = (size_t)Bn * Sn * Kn * sizeof(float);

    ushort* fTb  = (ushort*)d_ws;
    float*  mSm  = (float*)((char*)d_ws + fTb_b);
    float*  part = (float*)((char*)d_ws + fTb_b + mS_b);

    dim3 gg(HWn / TLH, Bn);     // (128, 2)
    gatherT_kernel<<<gg, 512, 0, stream>>>(masks, feats, indices, fTb, mSm);
    dim3 grid(NTRI, Bn);        // (528, 2)
    sim_kernel<<<grid, 256, 0, stream>>>(fTb, mSm, part);
    finalize_kernel<<<1, 256, 0, stream>>>(part, out);
}